// Round 3
// 303.930 us; speedup vs baseline: 1.0214x; 1.0214x over previous
//
#include <hip/hip_runtime.h>

#define NB    2048
#define N1    50
#define DIMC  256
#define NHEAD 8

typedef short  s16x8 __attribute__((ext_vector_type(8)));
typedef short  s16x4 __attribute__((ext_vector_type(4)));
typedef float  f32x4 __attribute__((ext_vector_type(4)));
typedef float  f32x2 __attribute__((ext_vector_type(2)));
typedef unsigned int u32x2 __attribute__((ext_vector_type(2)));

__device__ __forceinline__ unsigned short f2bf(float f) {
    unsigned int u = __builtin_bit_cast(unsigned int, f);
    u = (u + 0x7FFFu + ((u >> 16) & 1u)) >> 16;
    return (unsigned short)u;
}
__device__ __forceinline__ s16x8 ld8(const unsigned short* p) {
    return *(const s16x8*)p;   // 16B-aligned by construction
}

// ---------------- prep: K-blocked bf16 weights + padded mask ----------------
// wqkvB[ks][n][kk] = qkv_w[ks*32+kk][n]   (8 x 768 x 32 bf16, contiguous per ks)
// wprojB[ks][n][kk] = proj_w[ks*32+kk][n] (8 x 256 x 32 bf16)
// maskP[win][q][k]  (64x64x64 f32): pad keys k>=50 -> -1e30 (exp->0); pad queries -> 0
__global__ void prep_kernel(const float* __restrict__ qkv_w, const float* __restrict__ proj_w,
                            const float* __restrict__ mask,
                            unsigned short* __restrict__ wqkvB, unsigned short* __restrict__ wprojB,
                            float* __restrict__ maskP) {
    int idx = blockIdx.x * 256 + threadIdx.x;          // 0 .. 262143
    {
        int wv = idx >> 12, q = (idx >> 6) & 63, k = idx & 63;
        float v = (k < 50) ? ((q < 50) ? mask[(wv * 50 + q) * 50 + k] : 0.f) : -1e30f;
        maskP[idx] = v;
    }
    if (idx < 196608) {
        int ks = idx / 24576, rem = idx - ks * 24576, n = rem >> 5, kk = rem & 31;
        wqkvB[idx] = f2bf(qkv_w[(ks * 32 + kk) * 768 + n]);
    }
    if (idx < 65536) {
        int ks = idx >> 13, rem = idx & 8191, n = rem >> 5, kk = rem & 31;
        wprojB[idx] = f2bf(proj_w[(ks * 32 + kk) * 256 + n]);
    }
}

// ---------------- fully fused: QKV GEMM + attention + proj, one batch per block ----------------
// 1024 threads = 16 waves, LDS 152576 B (1 block/CU, 16 waves), 3 barriers.
// Operand-swapped MFMAs: Q/K (phase 1) and proj (phase 3) compute the TRANSPOSED tile
// (A = weight frag, B = xc frag) so each lane holds 4 consecutive feature values for a
// fixed token -> packed b64 LDS writes / dwordx4 global stores instead of scalar scatter.
// Wave->column map is tile-interleaved (wave w owns 16-col tiles {w, w+16, w+32}) so
// nt=0/1/2 are compile-time Q/K/V. All f32->bf16 conversions use f2bf (bit-identical
// to the verified baseline; cvt_pk deferred pending isolated A/B).
__global__ __launch_bounds__(1024, 4) void fused_kernel(
        const float* __restrict__ x, const float* __restrict__ cls,
        const float* __restrict__ qkv_b, const unsigned short* __restrict__ wqkvB,
        const unsigned short* __restrict__ wprojB, const float* __restrict__ proj_b,
        const float* __restrict__ maskP, float* __restrict__ out) {
    __shared__ __align__(16) char smem_raw[152576];
    unsigned short* S   = (unsigned short*)smem_raw;
    unsigned short* sXC = S;            // [64][264] xc bf16; later reused as sO (attention out)
    unsigned short* sQ  = S + 16896;    // [8][64][40]  (sP aliases dead half per head)
    unsigned short* sK  = S + 37376;    // [8][64][40]
    unsigned short* sVT = S + 57856;    // [8][32][72]  v^T [d][tok]

    const int b = blockIdx.x, tid = threadIdx.x;
    const int lane = tid & 63, w = tid >> 6;
    const int ln15 = lane & 15, quad = lane >> 4, q8 = quad * 8;
    const int win = b & 63;
    const float SCALE = 0.17677669529663687f;

    // ---- stage xc rows (row0=cls, 1..49=x, 50..63=0): one row per wave per iter,
    //      f32x4 load -> 4x f2bf -> one b64 LDS write (coalesced, conflict-free)
    #pragma unroll
    for (int it = 0; it < 4; ++it) {
        const int r = it * 16 + w;
        f32x4 t;
        if (r == 0)       t = *(const f32x4*)&cls[lane * 4];
        else if (r <= 49) t = *(const f32x4*)&x[((size_t)b * 49 + (r - 1)) * 256 + lane * 4];
        else              t = f32x4{0.f, 0.f, 0.f, 0.f};
        u32x2 wv;
        wv[0] = (unsigned int)f2bf(t[0]) | ((unsigned int)f2bf(t[1]) << 16);
        wv[1] = (unsigned int)f2bf(t[2]) | ((unsigned int)f2bf(t[3]) << 16);
        *(u32x2*)&sXC[r * 264 + lane * 4] = wv;
    }
    // ---- prefetch phase-1 B frags for ks=0 (global->reg, overlaps barrier)
    // column tile for nt: gc = nt*256 + w*16 + ln15  (nt=0 -> Q, 1 -> K, 2 -> V)
    s16x8 bcur[3];
    #pragma unroll
    for (int nt = 0; nt < 3; ++nt)
        bcur[nt] = ld8(wqkvB + (nt * 256 + w * 16 + ln15) * 32 + q8);
    __syncthreads();                                    // barrier 1

    // ================= phase 1: [64x256] @ [256x768], barrier-free K-loop =====
    f32x4 acc[4][3];
    #pragma unroll
    for (int mt = 0; mt < 4; ++mt)
        #pragma unroll
        for (int nt = 0; nt < 3; ++nt) acc[mt][nt] = f32x4{0.f, 0.f, 0.f, 0.f};

    #pragma unroll
    for (int ks = 0; ks < 8; ++ks) {
        s16x8 bnext[3];
        if (ks < 7) {
            const unsigned short* src = wqkvB + (ks + 1) * 24576;
            #pragma unroll
            for (int nt = 0; nt < 3; ++nt)
                bnext[nt] = ld8(src + (nt * 256 + w * 16 + ln15) * 32 + q8);
        }
        s16x8 af[4];
        #pragma unroll
        for (int mt = 0; mt < 4; ++mt)
            af[mt] = ld8(&sXC[(mt * 16 + ln15) * 264 + ks * 32 + q8]);
        #pragma unroll
        for (int mt = 0; mt < 4; ++mt) {
            // Q,K swapped: C[m=feature][n=token] -> lane holds 4 consecutive features
            acc[mt][0] = __builtin_amdgcn_mfma_f32_16x16x32_bf16(bcur[0], af[mt], acc[mt][0], 0, 0, 0);
            acc[mt][1] = __builtin_amdgcn_mfma_f32_16x16x32_bf16(bcur[1], af[mt], acc[mt][1], 0, 0, 0);
            // V unswapped: C[m=token][n=feature] -> packed writes into sVT[d][tok]
            acc[mt][2] = __builtin_amdgcn_mfma_f32_16x16x32_bf16(af[mt], bcur[2], acc[mt][2], 0, 0, 0);
        }
        if (ks < 7) {
            #pragma unroll
            for (int nt = 0; nt < 3; ++nt) bcur[nt] = bnext[nt];
        }
    }

    // ---- epilogue: bias (+scale for q); ALL writes are packed b64
    {
        const int hd = w >> 1, ddb = (w & 1) * 16;
        const f32x4 bq4 = *(const f32x4*)&qkv_b[w * 16 + quad * 4];
        const f32x4 bk4 = *(const f32x4*)&qkv_b[256 + w * 16 + quad * 4];
        const float bv  = qkv_b[512 + w * 16 + ln15];
        #pragma unroll
        for (int mt = 0; mt < 4; ++mt) {
            const int row = (mt * 16 + ln15) * 40 + ddb + quad * 4;
            s16x4 wq, wk, wv;
            #pragma unroll
            for (int i = 0; i < 4; ++i) {
                wq[i] = f2bf((acc[mt][0][i] + bq4[i]) * SCALE);
                wk[i] = f2bf(acc[mt][1][i] + bk4[i]);
                wv[i] = f2bf(acc[mt][2][i] + bv);
            }
            *(s16x4*)&sQ[hd * 2560 + row] = wq;
            *(s16x4*)&sK[hd * 2560 + row] = wk;
            *(s16x4*)&sVT[hd * 2304 + (ddb + ln15) * 72 + mt * 16 + quad * 4] = wv;
        }
    }
    __syncthreads();                                    // barrier 2

    // ================= phase 2: attention, wave = (head h, row-half rh), barrier-free =========
    {
        const int h = w >> 1, rh = w & 1, qt0 = rh * 2;
        // sP aliases this wave's own half of sQ[h] (read-before-write, same-wave in-order DS)
        unsigned short* sPw = sQ + h * 2560 + rh * 1280;

        s16x8 ak[4];
        #pragma unroll
        for (int kt = 0; kt < 4; ++kt)
            ak[kt] = ld8(&sK[h * 2560 + (kt * 16 + ln15) * 40 + q8]);

        f32x4 st[2][4];
        #pragma unroll
        for (int mt = 0; mt < 2; ++mt) {
            s16x8 bq = ld8(&sQ[h * 2560 + ((qt0 + mt) * 16 + ln15) * 40 + q8]);
            #pragma unroll
            for (int kt = 0; kt < 4; ++kt) {
                f32x4 z = {0.f, 0.f, 0.f, 0.f};
                st[mt][kt] = __builtin_amdgcn_mfma_f32_16x16x32_bf16(ak[kt], bq, z, 0, 0, 0);
            }
        }
        // S^T layout: col(=lane&15)=query, row(=quad*4+reg)=key
        s16x8 pb[2][2];
        #pragma unroll
        for (int mt = 0; mt < 2; ++mt) {
            float sum = 0.f;
            #pragma unroll
            for (int kt = 0; kt < 4; ++kt) {
                f32x4 mk = *(const f32x4*)&maskP[((size_t)(win * 64 + (qt0 + mt) * 16 + ln15)) * 64 + kt * 16 + quad * 4];
                #pragma unroll
                for (int i = 0; i < 4; ++i) {
                    float e = __expf(st[mt][kt][i] + mk[i]);   // no-max softmax; pad keys -> 0
                    st[mt][kt][i] = e;
                    sum += e;
                }
            }
            sum += __shfl_xor(sum, 16, 64);
            sum += __shfl_xor(sum, 32, 64);
            const float inv = 1.f / sum;
            #pragma unroll
            for (int kt = 0; kt < 4; ++kt) {
                s16x4 pk;
                #pragma unroll
                for (int i = 0; i < 4; ++i) pk[i] = f2bf(st[mt][kt][i] * inv);
                *(s16x4*)&sPw[ln15 * 72 + kt * 16 + quad * 4] = pk;   // P[query][key]
            }
            asm volatile("s_waitcnt lgkmcnt(0)" ::: "memory");
            pb[mt][0] = ld8(&sPw[ln15 * 72 + q8]);        // B-frag: P[query=ln15][key=q8+j]
            pb[mt][1] = ld8(&sPw[ln15 * 72 + 32 + q8]);
        }
        // O^T = V^T @ P^T : C/D col=query, row=d
        s16x8 av[2][2];
        #pragma unroll
        for (int dt = 0; dt < 2; ++dt)
            #pragma unroll
            for (int kk = 0; kk < 2; ++kk)
                av[dt][kk] = ld8(&sVT[h * 2304 + (dt * 16 + ln15) * 72 + kk * 32 + q8]);
        f32x4 o[2][2];
        #pragma unroll
        for (int mt = 0; mt < 2; ++mt)
            #pragma unroll
            for (int dt = 0; dt < 2; ++dt) o[mt][dt] = f32x4{0.f, 0.f, 0.f, 0.f};
        #pragma unroll
        for (int mt = 0; mt < 2; ++mt)
            #pragma unroll
            for (int dt = 0; dt < 2; ++dt)
                #pragma unroll
                for (int kk = 0; kk < 2; ++kk)
                    o[mt][dt] = __builtin_amdgcn_mfma_f32_16x16x32_bf16(av[dt][kk], pb[mt][kk], o[mt][dt], 0, 0, 0);
        // O -> LDS (sO aliases sXC, dead after barrier 2); packed b64 writes
        #pragma unroll
        for (int mt = 0; mt < 2; ++mt) {
            const int qg = (qt0 + mt) * 16 + ln15;
            #pragma unroll
            for (int dt = 0; dt < 2; ++dt) {
                s16x4 ov;
                #pragma unroll
                for (int i = 0; i < 4; ++i) ov[i] = f2bf(o[mt][dt][i]);
                *(s16x4*)&sXC[qg * 264 + h * 32 + dt * 16 + quad * 4] = ov;
            }
        }
    }
    // prefetch phase-3 ks=0 B frags (global, no LDS dep -> overlaps barrier 3)
    const int wm3 = w >> 3, wn3 = w & 7;                // wave tile: 32 rows x 32 cols
    s16x8 b3[2];
    #pragma unroll
    for (int nt = 0; nt < 2; ++nt)
        b3[nt] = ld8(wprojB + (wn3 * 32 + nt * 16 + ln15) * 32 + q8);
    __syncthreads();                                    // barrier 3

    // ================= phase 3: proj GEMM [64x256]@[256x256], swapped, barrier-free ============
    {
        f32x4 a3[2][2];
        #pragma unroll
        for (int mt = 0; mt < 2; ++mt)
            #pragma unroll
            for (int nt = 0; nt < 2; ++nt) a3[mt][nt] = f32x4{0.f, 0.f, 0.f, 0.f};
        #pragma unroll
        for (int ks = 0; ks < 8; ++ks) {
            s16x8 b3n[2];
            if (ks < 7) {
                const unsigned short* src = wprojB + (ks + 1) * 8192;
                #pragma unroll
                for (int nt = 0; nt < 2; ++nt)
                    b3n[nt] = ld8(src + (wn3 * 32 + nt * 16 + ln15) * 32 + q8);
            }
            s16x8 af3[2];
            #pragma unroll
            for (int mt = 0; mt < 2; ++mt)
                af3[mt] = ld8(&sXC[(wm3 * 32 + mt * 16 + ln15) * 264 + ks * 32 + q8]);
            #pragma unroll
            for (int mt = 0; mt < 2; ++mt)
                #pragma unroll
                for (int nt = 0; nt < 2; ++nt)   // swapped: C[m=projcol][n=token]
                    a3[mt][nt] = __builtin_amdgcn_mfma_f32_16x16x32_bf16(b3[nt], af3[mt], a3[mt][nt], 0, 0, 0);
            if (ks < 7) {
                #pragma unroll
                for (int nt = 0; nt < 2; ++nt) b3[nt] = b3n[nt];
            }
        }
        // epilogue: bias + predicated dwordx4 stores (row 0 -> out[:,0], rows 1..49 -> out[:,1:])
        #pragma unroll
        for (int nt = 0; nt < 2; ++nt) {
            const int cb = wn3 * 32 + nt * 16 + quad * 4;
            const f32x4 b4 = *(const f32x4*)&proj_b[cb];
            #pragma unroll
            for (int mt = 0; mt < 2; ++mt) {
                const int t = wm3 * 32 + mt * 16 + ln15;
                f32x4 v;
                #pragma unroll
                for (int i = 0; i < 4; ++i) v[i] = a3[mt][nt][i] + b4[i];
                if (t == 0)      *(f32x4*)&out[(size_t)b * 256 + cb] = v;
                else if (t < 50) *(f32x4*)&out[524288 + ((size_t)b * 49 + (t - 1)) * 256 + cb] = v;
            }
        }
    }
}

extern "C" void kernel_launch(void* const* d_in, const int* in_sizes, int n_in,
                              void* d_out, int out_size, void* d_ws, size_t ws_size,
                              hipStream_t stream) {
    const float* x      = (const float*)d_in[0];
    const float* mask   = (const float*)d_in[1];
    const float* cls    = (const float*)d_in[2];
    const float* qkv_w  = (const float*)d_in[3];
    const float* qkv_b  = (const float*)d_in[4];
    const float* proj_w = (const float*)d_in[5];
    const float* proj_b = (const float*)d_in[6];
    float* out = (float*)d_out;

    // workspace layout (1.57 MB)
    unsigned short* wqkvB  = (unsigned short*)d_ws;                        // 393,216 B
    unsigned short* wprojB = (unsigned short*)((char*)d_ws + 393216);      // 131,072 B
    float*          maskP  = (float*)((char*)d_ws + 524288);               // 1,048,576 B

    prep_kernel<<<1024, 256, 0, stream>>>(qkv_w, proj_w, mask, wqkvB, wprojB, maskP);
    fused_kernel<<<NB, 1024, 0, stream>>>(x, cls, qkv_b, wqkvB, wprojB, proj_b, maskP, out);
}